// Round 7
// baseline (206.251 us; speedup 1.0000x reference)
//
#include <hip/hip_runtime.h>
#include <hip/hip_bf16.h>

typedef __attribute__((ext_vector_type(8))) short bf16x8;
typedef __attribute__((ext_vector_type(4))) float f32x4;
typedef __attribute__((ext_vector_type(16))) float f32x16;

namespace {

__device__ __forceinline__ unsigned short f2bf(float f) {
  unsigned int x;
  __builtin_memcpy(&x, &f, 4);
  x += 0x7fff + ((x >> 16) & 1);  // round-to-nearest-even
  return (unsigned short)(x >> 16);
}
__device__ __forceinline__ unsigned int pack2(float a, float b) {
  return (unsigned int)f2bf(a) | ((unsigned int)f2bf(b) << 16);
}

// ============================ fused kernel ============================
// v8 = v7 with ONE structural change: head-granularity weight staging.
// R6 evidence: main loop = 24 tiles x 2 barriers = 48 block-wide barriers
// with only 16 MFMAs between pairs -> ~95% stall (MfmaUtil 12.6, all else
// idle). v8 stages Q,K,V tiles of a head per phase (dbuf 3-tile groups,
// LDS 158.7KB -- R4 proved >64KB static works; grid=256 forces 1 block/CU
// anyway) -> 2 barriers/HEAD (16 total), 48 MFMAs + full softmax per phase.
// Register deltas: prefetch packed to bf16 at load (6 uint4, +24 VGPR not
// +48); Q/K/V accs consumed immediately into per-s site slices (one f32x16
// live at a time, -32 VGPR); sites widened to hold both s.
// Phase X, MFMA math, softmax, epilogue byte-identical to v7.
constexpr int kWBStride = 264;             // 256 + 8 pad (elems)
constexpr int kWBTile = 32 * kWBStride;    // 8448 elems per tile
constexpr int kWG = 3 * kWBTile;           // 25344 elems (Q,K,V of one head)
constexpr int kSite = 3584;                // qb[2]640 | kb[2]640 (P s24) | vt[2]512
constexpr int kSmem = 2 * kWG + 8 * kSite; // 79360 elems = 158720 B
constexpr int kPanelStride = 72;           // x-panel row stride (16B-aligned b128)
constexpr int kWTileOff = 17408;           // shorts; after fbuf (512*17 floats)
static_assert(kSmem * 2 <= 160 * 1024, "LDS within 160KiB/CU");
static_assert(16 * 16 * kPanelStride <= kWG, "x panel fits in WG0");
static_assert(kWTileOff + kWBTile <= kSmem, "wout tile fits after fbuf");

__global__ __launch_bounds__(512, 1) void attn_fused(
    const float* __restrict__ x,     // (4,16,256,32,32) fp32
    const float* __restrict__ rel,   // (8,16,16) fp32
    const float* __restrict__ wqkv,  // (768,256) fp32
    const float* __restrict__ bqkv,  // (768,) fp32
    const float* __restrict__ wout,  // (256,256) fp32
    const float* __restrict__ bout,  // (256,) fp32
    float* __restrict__ out) {       // (4,16,256,32,32) fp32
  __shared__ __align__(16) unsigned short smem[kSmem];
  const int tid = threadIdx.x;
  const int lane = tid & 63;
  const int wave = tid >> 6;
  const int quad = lane >> 4;
  const int lrow = lane & 15;
  const int half = lane >> 5;
  const int n32 = lane & 31;
  const int b = blockIdx.x >> 6;
  const int hw0 = (blockIdx.x & 63) * 16;

  // ---- weight prefetch ids; load+pack tile group 0 (heads' tiles g=3h+u,
  // rows (g%3)*256 + (g/3)*32 + wrow of wqkv) ----
  const int wrow = tid >> 4;         // 0..31
  const int wcol = (tid & 15) * 16;  // 0..240
  uint4 pwp[6];                      // 3 tiles x 32B bf16 per thread
  auto loadpack = [&](int g, uint4& lo, uint4& hi) {
    const int rowbase = (g % 3) * 256 + (g / 3) * 32;
    const float* sp = wqkv + (size_t)(rowbase + wrow) * 256 + wcol;
    const float4 v0 = ((const float4*)sp)[0];
    const float4 v1 = ((const float4*)sp)[1];
    const float4 v2 = ((const float4*)sp)[2];
    const float4 v3 = ((const float4*)sp)[3];
    lo.x = pack2(v0.x, v0.y); lo.y = pack2(v0.z, v0.w);
    lo.z = pack2(v1.x, v1.y); lo.w = pack2(v1.z, v1.w);
    hi.x = pack2(v2.x, v2.y); hi.y = pack2(v2.z, v2.w);
    hi.z = pack2(v3.x, v3.y); hi.w = pack2(v3.z, v3.w);
  };
#pragma unroll
  for (int u = 0; u < 3; ++u) loadpack(u, pwp[2 * u], pwp[2 * u + 1]);

  // ---- phase X: stage x into bf16 panel, extract A-frags (v7-identical) ----
  // ax semantics: A[m=n32][k=ks*16+half*8+j] =
  //   x_bf16[b][t=lrow][c=k][hw = hw0 + 2*wave + (n32>>4)]
  bf16x8 ax[16];
  {
    unsigned short* panel = smem;
    const int sloc = wave * 2 + (n32 >> 4);
#pragma unroll
    for (int cc4 = 0; cc4 < 4; ++cc4) {  // full unroll: ax statically indexed
      const int c0 = cc4 * 64;
      __syncthreads();  // panel free (prev chunk's readers done)
#pragma unroll
      for (int u = 0; u < 8; ++u) {
        const int idx = u * 512 + tid;
        const int row = idx >> 2;  // t*64 + cl
        const int q = idx & 3;     // which 4-hw chunk
        const int t = row >> 6;
        const int cl = row & 63;
        const float4 v = *(const float4*)(
            x + (((size_t)(b * 16 + t) * 256 + c0 + cl) << 10) + hw0 + q * 4);
        unsigned short* pr = panel + (t * 16 + q * 4) * kPanelStride + cl;
        pr[0] = f2bf(v.x);
        pr[kPanelStride] = f2bf(v.y);
        pr[2 * kPanelStride] = f2bf(v.z);
        pr[3 * kPanelStride] = f2bf(v.w);
      }
      __syncthreads();  // panel ready
#pragma unroll
      for (int kk = 0; kk < 4; ++kk)
        ax[cc4 * 4 + kk] = *(const bf16x8*)(
            panel + (lrow * 16 + sloc) * kPanelStride + kk * 16 + half * 8);
    }
  }
  // head_phase(0)'s first barrier protects panel region before WG0 writes.

  unsigned short* qb = smem + 2 * kWG + wave * kSite;  // [s]: +s*640
  unsigned short* kb = qb + 1280;                      // [s]: +s*640
  unsigned short* vt = qb + 2560;                      // [s]: +s*512

  const int stageDst = wrow * kWBStride + wcol;
  const f32x4 zero4 = {0.f, 0.f, 0.f, 0.f};
  const float scale = 0.17677669529663687f;  // 32^-0.5
  bf16x8 ao[2][8];

  // 16-kstep 32x32x16 MFMA over one staged 32x256 tile
  auto mfma16 = [&](const unsigned short* WT, float bias) -> f32x16 {
    f32x16 acc;
#pragma unroll
    for (int i = 0; i < 16; ++i) acc[i] = bias;
    const unsigned short* br = WT + n32 * kWBStride + half * 8;
#pragma unroll
    for (int ks = 0; ks < 16; ++ks) {
      const bf16x8 bf = *(const bf16x8*)(br + ks * 16);
      acc = __builtin_amdgcn_mfma_f32_32x32x16_bf16(ax[ks], bf, acc, 0, 0, 0);
    }
    return acc;
  };

  // one head per phase, h literal at each call site
  auto head_phase = [&](int h) {
    __syncthreads();  // WG[h&1] free (its readers finished >=1 phase ago)
    unsigned short* WGc = smem + (h & 1) * kWG;
#pragma unroll
    for (int u = 0; u < 3; ++u) {
      *(uint4*)(WGc + u * kWBTile + stageDst) = pwp[2 * u];
      *(uint4*)(WGc + u * kWBTile + stageDst + 8) = pwp[2 * u + 1];
    }
#pragma unroll
    for (int u = 0; u < 3; ++u) {  // prefetch head h+1 (clamped; dummy at h=7)
      int gt = 3 * (h + 1) + u;
      if (gt > 23) gt = 23;
      loadpack(gt, pwp[2 * u], pwp[2 * u + 1]);
    }
    __syncthreads();  // WG[h&1] ready

    // Q: C/D 32x32 reg=8s+rr -> row=16s+t, t=(rr&3)+8*(rr>>2)+4*half, col=n32
    {
      const f32x16 qacc = mfma16(WGc, bqkv[h * 32 + n32]);
#pragma unroll
      for (int s = 0; s < 2; ++s)
#pragma unroll
        for (int rr = 0; rr < 8; ++rr) {
          const int t = (rr & 3) + 8 * (rr >> 2) + 4 * half;
          qb[s * 640 + t * 40 + n32] = f2bf(qacc[8 * s + rr]);
        }
    }
    // K
    {
      const f32x16 kacc = mfma16(WGc + kWBTile, bqkv[256 + h * 32 + n32]);
#pragma unroll
      for (int s = 0; s < 2; ++s)
#pragma unroll
        for (int rr = 0; rr < 8; ++rr) {
          const int t = (rr & 3) + 8 * (rr >> 2) + 4 * half;
          kb[s * 640 + t * 40 + n32] = f2bf(kacc[8 * s + rr]);
        }
    }
    // V -> vt[s][d=n32][j=t] (stride 16), paired t writes (b32)
    {
      const f32x16 vacc = mfma16(WGc + 2 * kWBTile, bqkv[512 + h * 32 + n32]);
#pragma unroll
      for (int s = 0; s < 2; ++s)
#pragma unroll
        for (int rp = 0; rp < 4; ++rp) {
          const int rr = rp * 2;
          const int t = (rr & 3) + 8 * (rr >> 2) + 4 * half;
          *(unsigned int*)&vt[s * 512 + n32 * 16 + t] =
              pack2(vacc[8 * s + rr], vacc[8 * s + rr + 1]);
        }
    }

    float rl[4];
#pragma unroll
    for (int r = 0; r < 4; ++r) rl[r] = rel[h * 256 + (quad * 4 + r) * 16 + lrow];

#pragma unroll
    for (int s = 0; s < 2; ++s) {
      // sim (16x16x32): A=q[m=t][k=d], B[k=d][n=j]=k[j][d]
      const bf16x8 qf = *(const bf16x8*)(qb + s * 640 + lrow * 40 + quad * 8);
      const bf16x8 kf = *(const bf16x8*)(kb + s * 640 + lrow * 40 + quad * 8);
      const f32x4 sim = __builtin_amdgcn_mfma_f32_16x16x32_bf16(qf, kf, zero4, 0, 0, 0);
      float p[4], inv[4];
#pragma unroll
      for (int r = 0; r < 4; ++r) {
        const float v = sim[r] * scale + rl[r];
        float m = v;
        for (int off = 8; off; off >>= 1) m = fmaxf(m, __shfl_xor(m, off));
        const float e = __expf(v - m);
        float sum = e;
        for (int off = 8; off; off >>= 1) sum += __shfl_xor(sum, off);
        p[r] = e;
        inv[r] = 1.0f / sum;
      }
      unsigned short* pb = kb + s * 640;  // P overlays this s's k (dead), stride 24
#pragma unroll
      for (int r = 0; r < 4; ++r) pb[(quad * 4 + r) * 24 + lrow] = f2bf(p[r]);
      bf16x8 pf, vf0, vf1;
      if (quad < 2) {
        pf = *(const bf16x8*)(pb + lrow * 24 + quad * 8);
        vf0 = *(const bf16x8*)(vt + s * 512 + lrow * 16 + quad * 8);
        vf1 = *(const bf16x8*)(vt + s * 512 + (16 + lrow) * 16 + quad * 8);
      } else {
#pragma unroll
        for (int j = 0; j < 8; ++j) { pf[j] = 0; vf0[j] = 0; vf1[j] = 0; }
      }
      const f32x4 o0 = __builtin_amdgcn_mfma_f32_16x16x32_bf16(pf, vf0, zero4, 0, 0, 0);
      const f32x4 o1 = __builtin_amdgcn_mfma_f32_16x16x32_bf16(pf, vf1, zero4, 0, 0, 0);
#pragma unroll
      for (int r = 0; r < 4; ++r) {  // O bounce into qb_s (dead) -> A-layout
        const int t = quad * 4 + r;
        qb[s * 640 + t * 40 + lrow] = f2bf(o0[r] * inv[r]);
        qb[s * 640 + t * 40 + 16 + lrow] = f2bf(o1[r] * inv[r]);
      }
      ao[s][h] = *(const bf16x8*)(qb + s * 640 + lrow * 40 + quad * 8);
    }
  };

  // fully unrolled heads: literal h -> ao[][] statically indexed (registers)
  head_phase(0);
  head_phase(1);
  head_phase(2);
  head_phase(3);
  head_phase(4);
  head_phase(5);
  head_phase(6);
  head_phase(7);

  // ---- epilogue: y = O @ wout^T + bout (v7-identical) ----
  // Per cc: stage wout rows cc*32..+32 once to LDS bf16 (16 f2bf/thread),
  // MFMA reads b128 from padded tile, fbuf bounce, 64-B coalesced stores.
  __syncthreads();  // WG/site readers done; fbuf+wtile overlay smem
  float* fbuf = (float*)smem;                 // 512 lines x 17 floats
  unsigned short* wtile = smem + kWTileOff;   // 32 x 264 bf16
  float* ob = out + ((size_t)b << 22);
#pragma unroll 1
  for (int cc = 0; cc < 8; ++cc) {
    {
      const float* sp = wout + (size_t)(cc * 32 + wrow) * 256 + wcol;
      const float4 v0 = ((const float4*)sp)[0];
      const float4 v1 = ((const float4*)sp)[1];
      const float4 v2 = ((const float4*)sp)[2];
      const float4 v3 = ((const float4*)sp)[3];
      uint4 a, bq;
      a.x = pack2(v0.x, v0.y);
      a.y = pack2(v0.z, v0.w);
      a.z = pack2(v1.x, v1.y);
      a.w = pack2(v1.z, v1.w);
      bq.x = pack2(v2.x, v2.y);
      bq.y = pack2(v2.z, v2.w);
      bq.z = pack2(v3.x, v3.y);
      bq.w = pack2(v3.z, v3.w);
      unsigned short* d = wtile + wrow * kWBStride + wcol;
      *(uint4*)d = a;
      *(uint4*)(d + 8) = bq;
    }
    __syncthreads();  // wtile ready
#pragma unroll
    for (int sub = 0; sub < 2; ++sub) {
      const int c = cc * 32 + sub * 16 + lrow;
      const float bias = bout[c];
      f32x4 y0 = {bias, bias, bias, bias};
      f32x4 y1 = {bias, bias, bias, bias};
      const unsigned short* wrow_p = wtile + (sub * 16 + lrow) * kWBStride;
#pragma unroll
      for (int ks = 0; ks < 8; ++ks) {
        const bf16x8 wf = *(const bf16x8*)(wrow_p + ks * 32 + quad * 8);
        y0 = __builtin_amdgcn_mfma_f32_16x16x32_bf16(ao[0][ks], wf, y0, 0, 0, 0);
        y1 = __builtin_amdgcn_mfma_f32_16x16x32_bf16(ao[1][ks], wf, y1, 0, 0, 0);
      }
#pragma unroll
      for (int r = 0; r < 4; ++r) {
        const int t = quad * 4 + r;
        const int L = (t * 32 + sub * 16 + lrow) * 17 + wave * 2;
        fbuf[L] = y0[r];
        fbuf[L + 1] = y1[r];
      }
    }
    __syncthreads();
    {
      const int t = tid >> 5, cl = tid & 31;
      float v[16];
#pragma unroll
      for (int i = 0; i < 16; ++i) v[i] = fbuf[tid * 17 + i];
      float* dst = ob + ((size_t)(t * 256 + cc * 32 + cl)) * 1024 + hw0;
#pragma unroll
      for (int u = 0; u < 4; ++u) {
        float4 q;
        q.x = v[u * 4]; q.y = v[u * 4 + 1]; q.z = v[u * 4 + 2]; q.w = v[u * 4 + 3];
        *(float4*)(dst + u * 4) = q;
      }
    }
    __syncthreads();  // fbuf+wtile free for next cc
  }
}

}  // namespace

extern "C" void kernel_launch(void* const* d_in, const int* in_sizes, int n_in,
                              void* d_out, int out_size, void* d_ws, size_t ws_size,
                              hipStream_t stream) {
  const float* x = (const float*)d_in[0];
  const float* rel = (const float*)d_in[1];
  const float* wqkv = (const float*)d_in[2];
  const float* bqkv = (const float*)d_in[3];
  const float* wout = (const float*)d_in[4];
  const float* bout = (const float*)d_in[5];
  float* out = (float*)d_out;
  (void)in_sizes; (void)n_in; (void)out_size; (void)d_ws; (void)ws_size;

  attn_fused<<<256, 512, 0, stream>>>(x, rel, wqkv, bqkv, wout, bout, out);
}

// Round 8
// 202.478 us; speedup vs baseline: 1.0186x; 1.0186x over previous
//
#include <hip/hip_runtime.h>
#include <hip/hip_bf16.h>

typedef __attribute__((ext_vector_type(8))) short bf16x8;
typedef __attribute__((ext_vector_type(4))) float f32x4;
typedef __attribute__((ext_vector_type(16))) float f32x16;

namespace {

__device__ __forceinline__ unsigned short f2bf(float f) {
  unsigned int x;
  __builtin_memcpy(&x, &f, 4);
  x += 0x7fff + ((x >> 16) & 1);  // round-to-nearest-even
  return (unsigned short)(x >> 16);
}
__device__ __forceinline__ unsigned int pack2(float a, float b) {
  return (unsigned int)f2bf(a) | ((unsigned int)f2bf(b) << 16);
}

// ============================ fused kernel ============================
// v9 = v7 (R6, best: 111us) + two surgical fixes from the R7 post-mortem
// (barrier-count exonerated; stall = dependent-MFMA-chain latency at
// 2 waves/SIMD + 4-way vt bank conflict):
//  (a) 16-deep MFMA accumulate split into two independent 8-chains
//      (even/odd ks; accA=bias-init, accB=0-init, summed at end): 2x pipe
//      ILP per wave where the latency chain lives. +16 transient VGPR.
//  (b) vt stride 16 -> 20 shorts (40B): PV read bank-starts
//      (10*lrow+4*quad)%32 all-distinct => ~1-2-way instead of 4-way.
//      kSite 1824 -> 1920 (kSmem 64512B <= 64KB).
// Everything else byte-identical to v7/R6.
constexpr int kWBStride = 264;                 // 256 + 8 pad (elems)
constexpr int kWBTile = 32 * kWBStride;        // 8448 elems
constexpr int kWB = 2 * kWBTile;               // 16896 elems
constexpr int kSite = 1920;                    // q640(s40)|k640(s40,P s24)|vt640(s20)
constexpr int kSmem = kWB + 8 * kSite;         // 32256 elems = 64512 B
constexpr int kPanelStride = 72;               // (t,hw) row stride; 144B: 16B-aligned b128 reads
constexpr int kWTileOff = 17408;               // shorts; after fbuf (512*17 floats)
static_assert(kSmem * 2 <= 65536, "LDS budget");
static_assert(16 * 16 * kPanelStride <= kSmem, "x panel fits");
static_assert(512 * 17 * 4 <= kSmem * 2, "fbuf fits");
static_assert(kWTileOff + kWBTile <= kSmem, "wout tile fits after fbuf");

__global__ __launch_bounds__(512, 1) void attn_fused(
    const float* __restrict__ x,     // (4,16,256,32,32) fp32
    const float* __restrict__ rel,   // (8,16,16) fp32
    const float* __restrict__ wqkv,  // (768,256) fp32
    const float* __restrict__ bqkv,  // (768,) fp32
    const float* __restrict__ wout,  // (256,256) fp32
    const float* __restrict__ bout,  // (256,) fp32
    float* __restrict__ out) {       // (4,16,256,32,32) fp32
  __shared__ __align__(16) unsigned short smem[kSmem];
  const int tid = threadIdx.x;
  const int lane = tid & 63;
  const int wave = tid >> 6;
  const int quad = lane >> 4;
  const int lrow = lane & 15;
  const int half = lane >> 5;
  const int n32 = lane & 31;
  const int b = blockIdx.x >> 6;
  const int hw0 = (blockIdx.x & 63) * 16;

  // ---- weight staging ids + early prefetch of QKV tile 0 (fp32) ----
  // tile g rows = wqkv rows (g%3)*256 + (g/3)*32 .. +32 (valid for g<=24)
  const int wrow = tid >> 4;         // 0..31
  const int wcol = (tid & 15) * 16;  // 0..240
  float4 pw[4];
  {
    const float* sp = wqkv + (size_t)wrow * 256 + wcol;  // rowbase(0)=0
#pragma unroll
    for (int u = 0; u < 4; ++u) pw[u] = *(const float4*)(sp + u * 4);
  }

  // ---- phase X: stage x into bf16 panel, extract A-frags ----
  // ax semantics (R2-identical): A[m=n32][k=ks*16+half*8+j] =
  //   x_bf16[b][t=lrow][c=k][hw = hw0 + 2*wave + (n32>>4)]
  bf16x8 ax[16];
  {
    unsigned short* panel = smem;
    const int sloc = wave * 2 + (n32 >> 4);
#pragma unroll
    for (int cc4 = 0; cc4 < 4; ++cc4) {  // full unroll: ax statically indexed
      const int c0 = cc4 * 64;
      __syncthreads();  // panel free (prev chunk's readers done)
#pragma unroll
      for (int u = 0; u < 8; ++u) {
        const int idx = u * 512 + tid;
        const int row = idx >> 2;  // t*64 + cl
        const int q = idx & 3;     // which 4-hw chunk
        const int t = row >> 6;
        const int cl = row & 63;
        const float4 v = *(const float4*)(
            x + (((size_t)(b * 16 + t) * 256 + c0 + cl) << 10) + hw0 + q * 4);
        unsigned short* pr = panel + (t * 16 + q * 4) * kPanelStride + cl;
        pr[0] = f2bf(v.x);
        pr[kPanelStride] = f2bf(v.y);
        pr[2 * kPanelStride] = f2bf(v.z);
        pr[3 * kPanelStride] = f2bf(v.w);
      }
      __syncthreads();  // panel ready
#pragma unroll
      for (int kk = 0; kk < 4; ++kk)
        ax[cc4 * 4 + kk] = *(const bf16x8*)(
            panel + (lrow * 16 + sloc) * kPanelStride + kk * 16 + half * 8);
    }
  }
  // qkv_tile(0)'s first barrier protects panel region before WB0 writes.

  unsigned short* qb = smem + kWB + wave * kSite;
  unsigned short* kb = qb + 640;
  unsigned short* vt = qb + 1280;  // stride 20, [d][j]

  const f32x4 zero4 = {0.f, 0.f, 0.f, 0.f};
  const float scale = 0.17677669529663687f;  // 32^-0.5
  bf16x8 ao[2][8];

  // staged QKV tile: write pw -> WB[g&1] (bf16), prefetch tile g+1 (fp32),
  // 16-kstep 32x32x16 MFMA as TWO independent 8-chains (even/odd ks).
  auto qkv_tile = [&](int g, float bias) -> f32x16 {
    __syncthreads();  // WB[g&1] free (consumers of g-2 done)
    unsigned short* WBc = smem + (g & 1) * kWBTile;
    {
      unsigned short* dst = WBc + wrow * kWBStride + wcol;
      uint4 a, bq;
      a.x = pack2(pw[0].x, pw[0].y);
      a.y = pack2(pw[0].z, pw[0].w);
      a.z = pack2(pw[1].x, pw[1].y);
      a.w = pack2(pw[1].z, pw[1].w);
      bq.x = pack2(pw[2].x, pw[2].y);
      bq.y = pack2(pw[2].z, pw[2].w);
      bq.z = pack2(pw[3].x, pw[3].y);
      bq.w = pack2(pw[3].z, pw[3].w);
      *(uint4*)dst = a;
      *(uint4*)(dst + 8) = bq;
    }
    {
      const int gn = g + 1;  // gn==24 -> rows 256..287: valid wqkv memory
      const int rowbase = (gn % 3) * 256 + (gn / 3) * 32;
      const float* sp = wqkv + (size_t)(rowbase + wrow) * 256 + wcol;
#pragma unroll
      for (int u = 0; u < 4; ++u) pw[u] = *(const float4*)(sp + u * 4);
    }
    __syncthreads();  // WB[g&1] ready
    f32x16 accA, accB;
#pragma unroll
    for (int i = 0; i < 16; ++i) { accA[i] = bias; accB[i] = 0.f; }
    const unsigned short* br = WBc + n32 * kWBStride + half * 8;
#pragma unroll
    for (int kp = 0; kp < 8; ++kp) {  // two independent dep-chains
      const bf16x8 bfa = *(const bf16x8*)(br + (2 * kp) * 16);
      const bf16x8 bfb = *(const bf16x8*)(br + (2 * kp + 1) * 16);
      accA = __builtin_amdgcn_mfma_f32_32x32x16_bf16(ax[2 * kp], bfa, accA, 0, 0, 0);
      accB = __builtin_amdgcn_mfma_f32_32x32x16_bf16(ax[2 * kp + 1], bfb, accB, 0, 0, 0);
    }
#pragma unroll
    for (int i = 0; i < 16; ++i) accA[i] += accB[i];
    return accA;
  };

  // one head, h literal at each call site (R6-identical body, vt stride 20)
  auto head_body = [&](int h) {
    const f32x16 qacc = qkv_tile(h * 3 + 0, bqkv[h * 32 + n32]);
    const f32x16 kacc = qkv_tile(h * 3 + 1, bqkv[256 + h * 32 + n32]);
    const f32x16 vacc = qkv_tile(h * 3 + 2, bqkv[512 + h * 32 + n32]);
    float rl[4];
#pragma unroll
    for (int r = 0; r < 4; ++r) rl[r] = rel[h * 256 + (quad * 4 + r) * 16 + lrow];

#pragma unroll
    for (int s = 0; s < 2; ++s) {
      // C/D 32x32: reg=8s+rr -> row=16s+t, t=(rr&3)+8*(rr>>2)+4*half, col=n32
#pragma unroll
      for (int rr = 0; rr < 8; ++rr) {
        const int t = (rr & 3) + 8 * (rr >> 2) + 4 * half;
        qb[t * 40 + n32] = f2bf(qacc[8 * s + rr]);
        kb[t * 40 + n32] = f2bf(kacc[8 * s + rr]);
      }
#pragma unroll
      for (int rp = 0; rp < 4; ++rp) {  // vT[d][j] stride 20, paired t (b32)
        const int rr = rp * 2;
        const int t = (rr & 3) + 8 * (rr >> 2) + 4 * half;
        *(unsigned int*)&vt[n32 * 20 + t] =
            pack2(vacc[8 * s + rr], vacc[8 * s + rr + 1]);
      }
      // sim (16x16x32): A=q[m=t][k=d], B[k=d][n=j]=k[j][d]
      const bf16x8 qf = *(const bf16x8*)(qb + lrow * 40 + quad * 8);
      const bf16x8 kf = *(const bf16x8*)(kb + lrow * 40 + quad * 8);
      const f32x4 sim = __builtin_amdgcn_mfma_f32_16x16x32_bf16(qf, kf, zero4, 0, 0, 0);
      float p[4], inv[4];
#pragma unroll
      for (int r = 0; r < 4; ++r) {
        const float v = sim[r] * scale + rl[r];
        float m = v;
        for (int off = 8; off; off >>= 1) m = fmaxf(m, __shfl_xor(m, off));
        const float e = __expf(v - m);
        float sum = e;
        for (int off = 8; off; off >>= 1) sum += __shfl_xor(sum, off);
        p[r] = e;
        inv[r] = 1.0f / sum;
      }
      unsigned short* pb = kb;  // P overlays k (dead), stride 24
#pragma unroll
      for (int r = 0; r < 4; ++r) pb[(quad * 4 + r) * 24 + lrow] = f2bf(p[r]);
      bf16x8 pf, vf0, vf1;
      if (quad < 2) {
        pf = *(const bf16x8*)(pb + lrow * 24 + quad * 8);
        vf0 = *(const bf16x8*)(vt + lrow * 20 + quad * 8);
        vf1 = *(const bf16x8*)(vt + (16 + lrow) * 20 + quad * 8);
      } else {
#pragma unroll
        for (int j = 0; j < 8; ++j) { pf[j] = 0; vf0[j] = 0; vf1[j] = 0; }
      }
      const f32x4 o0 = __builtin_amdgcn_mfma_f32_16x16x32_bf16(pf, vf0, zero4, 0, 0, 0);
      const f32x4 o1 = __builtin_amdgcn_mfma_f32_16x16x32_bf16(pf, vf1, zero4, 0, 0, 0);
#pragma unroll
      for (int r = 0; r < 4; ++r) {  // O bounce into qb (dead) -> A-layout
        const int t = quad * 4 + r;
        qb[t * 40 + lrow] = f2bf(o0[r] * inv[r]);
        qb[t * 40 + 16 + lrow] = f2bf(o1[r] * inv[r]);
      }
      ao[s][h] = *(const bf16x8*)(qb + lrow * 40 + quad * 8);
    }
  };

  // fully unrolled heads: literal h -> ao[][] statically indexed (registers)
  head_body(0);
  head_body(1);
  head_body(2);
  head_body(3);
  head_body(4);
  head_body(5);
  head_body(6);
  head_body(7);

  // ---- epilogue: y = O @ wout^T + bout (R6-identical) ----
  // Per cc: stage wout rows cc*32..+32 once to LDS bf16 (16 f2bf/thread),
  // MFMA reads b128 from padded tile, fbuf bounce, 64-B coalesced stores.
  __syncthreads();  // sitebufs/WB dead; fbuf+wtile overlay smem
  float* fbuf = (float*)smem;                 // 512 lines x 17 floats
  unsigned short* wtile = smem + kWTileOff;   // 32 x 264 bf16
  float* ob = out + ((size_t)b << 22);
#pragma unroll 1
  for (int cc = 0; cc < 8; ++cc) {
    {
      const float* sp = wout + (size_t)(cc * 32 + wrow) * 256 + wcol;
      const float4 v0 = ((const float4*)sp)[0];
      const float4 v1 = ((const float4*)sp)[1];
      const float4 v2 = ((const float4*)sp)[2];
      const float4 v3 = ((const float4*)sp)[3];
      uint4 a, bq;
      a.x = pack2(v0.x, v0.y);
      a.y = pack2(v0.z, v0.w);
      a.z = pack2(v1.x, v1.y);
      a.w = pack2(v1.z, v1.w);
      bq.x = pack2(v2.x, v2.y);
      bq.y = pack2(v2.z, v2.w);
      bq.z = pack2(v3.x, v3.y);
      bq.w = pack2(v3.z, v3.w);
      unsigned short* d = wtile + wrow * kWBStride + wcol;
      *(uint4*)d = a;
      *(uint4*)(d + 8) = bq;
    }
    __syncthreads();  // wtile ready
#pragma unroll
    for (int sub = 0; sub < 2; ++sub) {
      const int c = cc * 32 + sub * 16 + lrow;
      const float bias = bout[c];
      f32x4 y0 = {bias, bias, bias, bias};
      f32x4 y1 = {bias, bias, bias, bias};
      const unsigned short* wrow_p = wtile + (sub * 16 + lrow) * kWBStride;
#pragma unroll
      for (int ks = 0; ks < 8; ++ks) {
        const bf16x8 wf = *(const bf16x8*)(wrow_p + ks * 32 + quad * 8);
        y0 = __builtin_amdgcn_mfma_f32_16x16x32_bf16(ao[0][ks], wf, y0, 0, 0, 0);
        y1 = __builtin_amdgcn_mfma_f32_16x16x32_bf16(ao[1][ks], wf, y1, 0, 0, 0);
      }
#pragma unroll
      for (int r = 0; r < 4; ++r) {
        const int t = quad * 4 + r;
        const int L = (t * 32 + sub * 16 + lrow) * 17 + wave * 2;
        fbuf[L] = y0[r];
        fbuf[L + 1] = y1[r];
      }
    }
    __syncthreads();
    {
      const int t = tid >> 5, cl = tid & 31;
      float v[16];
#pragma unroll
      for (int i = 0; i < 16; ++i) v[i] = fbuf[tid * 17 + i];
      float* dst = ob + ((size_t)(t * 256 + cc * 32 + cl)) * 1024 + hw0;
#pragma unroll
      for (int u = 0; u < 4; ++u) {
        float4 q;
        q.x = v[u * 4]; q.y = v[u * 4 + 1]; q.z = v[u * 4 + 2]; q.w = v[u * 4 + 3];
        *(float4*)(dst + u * 4) = q;
      }
    }
    __syncthreads();  // fbuf+wtile free for next cc
  }
}

}  // namespace

extern "C" void kernel_launch(void* const* d_in, const int* in_sizes, int n_in,
                              void* d_out, int out_size, void* d_ws, size_t ws_size,
                              hipStream_t stream) {
  const float* x = (const float*)d_in[0];
  const float* rel = (const float*)d_in[1];
  const float* wqkv = (const float*)d_in[2];
  const float* bqkv = (const float*)d_in[3];
  const float* wout = (const float*)d_in[4];
  const float* bout = (const float*)d_in[5];
  float* out = (float*)d_out;
  (void)in_sizes; (void)n_in; (void)out_size; (void)d_ws; (void)ws_size;

  attn_fused<<<256, 512, 0, stream>>>(x, rel, wqkv, bqkv, wout, bout, out);
}